// Round 3
// baseline (417.739 us; speedup 1.0000x reference)
//
#include <hip/hip_runtime.h>

#define NSEQ  9216
#define CDIM  192
#define KTILE 64
#define LOG2E 1.44269504088896f

typedef _Float16 h8_t  __attribute__((ext_vector_type(8)));
typedef _Float16 h4_t  __attribute__((ext_vector_type(4)));
typedef _Float16 h2_t  __attribute__((ext_vector_type(2)));
typedef float    f4_t  __attribute__((ext_vector_type(4)));
typedef float    f16v  __attribute__((ext_vector_type(16)));

// ---------------------------------------------------------------------------
// Kernel 0: Wq/Wk/Wv fp32 -> f16 Wh[3][192][192].  Wq pre-scaled by log2e so
// flash softmax can use raw v_exp_f32 (2^x) with no per-element mul.
// ---------------------------------------------------------------------------
__global__ __launch_bounds__(256) void wconv_kernel(
    const float* __restrict__ Wq, const float* __restrict__ Wk,
    const float* __restrict__ Wv, _Float16* __restrict__ Wh)
{
    int i = blockIdx.x * 256 + threadIdx.x;     // f4 index, 3*9216 total
    if (i >= 3 * 9216) return;
    const float* src = (i < 9216) ? Wq : (i < 18432 ? Wk : Wv);
    float s = (i < 9216) ? LOG2E : 1.f;
    int r = i % 9216;
    f4_t w = ((const f4_t*)src)[r];
    h4_t h = {(_Float16)(w[0]*s), (_Float16)(w[1]*s),
              (_Float16)(w[2]*s), (_Float16)(w[3]*s)};
    ((h4_t*)Wh)[i] = h;
}

// ---------------------------------------------------------------------------
// Kernel 1: QKV projection via 32x32x16 MFMA.
//   One wave per (mat, 32-seq chunk): 1728 waves (6.75/CU) for latency hiding.
// ---------------------------------------------------------------------------
__global__ __launch_bounds__(256) void proj_kernel(
    const float* __restrict__ x, const _Float16* __restrict__ Wh,
    const float* __restrict__ bq, const float* __restrict__ bk,
    const float* __restrict__ bv,
    _Float16* __restrict__ QT, _Float16* __restrict__ KT, _Float16* __restrict__ Vg)
{
    const int tid  = threadIdx.x;
    const int lane = tid & 63, wave = tid >> 6;
    const int L31  = lane & 31, hi = lane >> 5;
    const int idx  = blockIdx.x * 4 + wave;      // 0..1727
    const int mat  = idx / 576;
    const int rem  = idx % 576;
    const int b    = rem / 288;
    const int n0   = (rem % 288) * 32;
    const int n    = n0 + L31;

    // B-fragments: B[k=c = t*16 + hi*8 + j][col=seq=L31]
    h8_t bf[12];
    #pragma unroll
    for (int t = 0; t < 12; t++) {
        h8_t h;
        #pragma unroll
        for (int j = 0; j < 8; j++)
            h[j] = (_Float16)x[(size_t)(b * CDIM + t * 16 + hi * 8 + j) * NSEQ + n];
        bf[t] = h;
    }

    const _Float16* W = Wh + mat * CDIM * CDIM;
    const float* bias = (mat == 0) ? bq : (mat == 1 ? bk : bv);
    const float bscale = (mat == 0) ? LOG2E : 1.f;

    f16v acc[6];
    #pragma unroll
    for (int s = 0; s < 6; s++)
        #pragma unroll
        for (int r = 0; r < 16; r++) acc[s][r] = 0.f;

    #pragma unroll
    for (int t = 0; t < 12; t++) {
        #pragma unroll
        for (int s = 0; s < 6; s++) {
            h8_t a = *(const h8_t*)(W + (s * 32 + L31) * CDIM + t * 16 + hi * 8);
            acc[s] = __builtin_amdgcn_mfma_f32_32x32x16_f16(a, bf[t], acc[s], 0, 0, 0);
        }
    }

    if (mat < 2) {
        _Float16* dst = ((mat == 0) ? QT : KT) + ((size_t)b * NSEQ + n) * CDIM;
        #pragma unroll
        for (int s = 0; s < 6; s++) {
            #pragma unroll
            for (int g = 0; g < 4; g++) {
                f4_t bb = *(const f4_t*)&bias[s * 32 + 8 * g + 4 * hi];
                h4_t h = {(_Float16)(acc[s][4*g+0] + bb[0] * bscale),
                          (_Float16)(acc[s][4*g+1] + bb[1] * bscale),
                          (_Float16)(acc[s][4*g+2] + bb[2] * bscale),
                          (_Float16)(acc[s][4*g+3] + bb[3] * bscale)};
                *(h4_t*)(dst + s * 32 + 8 * g + 4 * hi) = h;
            }
        }
    } else {
        #pragma unroll
        for (int s = 0; s < 6; s++) {
            #pragma unroll
            for (int g = 0; g < 4; g++) {
                f4_t bb = *(const f4_t*)&bias[s * 32 + 8 * g + 4 * hi];
                #pragma unroll
                for (int r = 0; r < 4; r++) {
                    int o = s * 32 + 8 * g + 4 * hi + r;
                    Vg[((size_t)b * CDIM + o) * NSEQ + n] =
                        (_Float16)(acc[s][4*g+r] + bb[r]);
                }
            }
        }
    }
}

// ---------------------------------------------------------------------------
// Kernel 2: flash attention.  K A-frags straight from global (L1/L2-hot),
// V staged in LDS (reg-prefetched across the barrier), P via per-wave LDS.
// m,l tracked in log2 domain (Q pre-scaled by log2e).
// ---------------------------------------------------------------------------
template<int NSPLIT>
__global__ __launch_bounds__(256, 2) void flash_kernel(
    const _Float16* __restrict__ QT, const _Float16* __restrict__ KTg,
    const _Float16* __restrict__ Vg,
    _Float16* __restrict__ O_part, float* __restrict__ m_part, float* __restrict__ l_part)
{
    constexpr int KPS    = NSEQ / NSPLIT;
    constexpr int KITERS = KPS / KTILE;

    __shared__ __align__(16) _Float16 V_s[CDIM * 72];     // [c][key], 36 dw stride
    __shared__ __align__(16) _Float16 P_s[4 * 32 * 72];   // per-wave [q][key]
    __shared__ float alpha_s[4][32];

    const int tid  = threadIdx.x;
    const int lane = tid & 63, wave = tid >> 6;
    const int L31  = lane & 31, hi = lane >> 5;
    const int qtile = blockIdx.x, split = blockIdx.y, b = blockIdx.z;
    const int q0 = qtile * 128 + wave * 32;

    // resident Q B-fragments: B[k=c][col=q=L31]
    h8_t qf[12];
    const _Float16* qbase = QT + ((size_t)b * NSEQ + q0 + L31) * CDIM + hi * 8;
    #pragma unroll
    for (int t = 0; t < 12; t++) qf[t] = *(const h8_t*)(qbase + t * 16);

    f16v acc[6];
    #pragma unroll
    for (int s = 0; s < 6; s++)
        #pragma unroll
        for (int r = 0; r < 16; r++) acc[s][r] = 0.f;
    float m_run = -__builtin_inff();
    float l_run = 0.f;

    const _Float16* ksrc = KTg + ((size_t)b * NSEQ + split * KPS) * CDIM;
    const _Float16* vsrc = Vg + (size_t)b * CDIM * NSEQ + split * KPS;

    // V staging addresses are loop-invariant: thread covers (c, seg) pairs
    const _Float16* vgl[6];
    _Float16*       vds[6];
    #pragma unroll
    for (int t = 0; t < 6; t++) {
        int i = tid + t * 256;
        int c = i >> 3, seg = i & 7;
        vgl[t] = vsrc + (size_t)c * NSEQ + seg * 8;
        vds[t] = V_s + c * 72 + seg * 8;
    }

    h8_t vreg[6];
    #pragma unroll
    for (int t = 0; t < 6; t++) vreg[t] = *(const h8_t*)(vgl[t]);

    for (int kt = 0; kt < KITERS; kt++) {
        __syncthreads();                      // prev iter's V_s reads done
        #pragma unroll
        for (int t = 0; t < 6; t++) *(h8_t*)(vds[t]) = vreg[t];
        __syncthreads();                      // V_s ready
        if (kt + 1 < KITERS) {
            #pragma unroll
            for (int t = 0; t < 6; t++)
                vreg[t] = *(const h8_t*)(vgl[t] + (kt + 1) * KTILE);
        }

        // S^T = K_tile * Q, K A-frags from global (L1/L2)
        const _Float16* kbase = ksrc + (size_t)kt * KTILE * CDIM;
        f16v st[2];
        #pragma unroll
        for (int s = 0; s < 2; s++)
            #pragma unroll
            for (int r = 0; r < 16; r++) st[s][r] = 0.f;
        #pragma unroll
        for (int t = 0; t < 12; t++) {
            #pragma unroll
            for (int s = 0; s < 2; s++) {
                h8_t a = *(const h8_t*)(kbase + (s * 32 + L31) * CDIM + t * 16 + hi * 8);
                st[s] = __builtin_amdgcn_mfma_f32_32x32x16_f16(a, qf[t], st[s], 0, 0, 0);
            }
        }

        // online softmax (log2 domain): lane's query = L31
        float mx = st[0][0];
        #pragma unroll
        for (int s = 0; s < 2; s++)
            #pragma unroll
            for (int r = 0; r < 16; r++) mx = fmaxf(mx, st[s][r]);
        mx = fmaxf(mx, __shfl_xor(mx, 32));
        float m_new = fmaxf(m_run, mx);

        float p[32];
        float psum = 0.f;
        #pragma unroll
        for (int s = 0; s < 2; s++)
            #pragma unroll
            for (int r = 0; r < 16; r++) {
                float e = __builtin_exp2f(st[s][r] - m_new);
                p[s * 16 + r] = e;
                psum += e;
            }

        if (__any(m_new > m_run)) {
            float alpha = __builtin_exp2f(m_run - m_new);   // -inf -> 0 first iter
            l_run = l_run * alpha + psum;
            if (lane < 32) alpha_s[wave][lane] = alpha;
            __asm__ volatile("" ::: "memory");
            f4_t a4[4];
            #pragma unroll
            for (int g = 0; g < 4; g++)
                a4[g] = *(const f4_t*)&alpha_s[wave][8 * g + 4 * hi];
            #pragma unroll
            for (int cs = 0; cs < 6; cs++)
                #pragma unroll
                for (int r = 0; r < 16; r++) acc[cs][r] *= a4[r >> 2][r & 3];
        } else {
            l_run += psum;
        }
        m_run = m_new;

        // P -> LDS, [q][key] (key = s*32 + 8g + 4hi + r)
        _Float16* prow = P_s + wave * 32 * 72 + L31 * 72;
        #pragma unroll
        for (int s = 0; s < 2; s++)
            #pragma unroll
            for (int g = 0; g < 4; g++) {
                h4_t h = {(_Float16)p[s*16+4*g+0], (_Float16)p[s*16+4*g+1],
                          (_Float16)p[s*16+4*g+2], (_Float16)p[s*16+4*g+3]};
                *(h4_t*)(prow + s * 32 + 8 * g + 4 * hi) = h;
            }
        __asm__ volatile("" ::: "memory");

        // PV: O^T[q][c] += P[q][key] * V[c][key]
        #pragma unroll
        for (int ks = 0; ks < 4; ks++) {
            h8_t pa = *(const h8_t*)(prow + ks * 16 + hi * 8);
            #pragma unroll
            for (int cs = 0; cs < 6; cs++) {
                h8_t vb = *(const h8_t*)(V_s + (cs * 32 + L31) * 72 + ks * 16 + hi * 8);
                acc[cs] = __builtin_amdgcn_mfma_f32_32x32x16_f16(pa, vb, acc[cs], 0, 0, 0);
            }
        }
    }

    // epilogue: unnormalized partials
    float l_tot = l_run + __shfl_xor(l_run, 32);
    const size_t pbase = (size_t)(b * NSPLIT + split) * NSEQ + q0;
    if (lane < 32) {
        m_part[pbase + lane] = m_run;
        l_part[pbase + lane] = l_tot;
    }
    _Float16* obase = O_part + pbase * CDIM;
    #pragma unroll
    for (int cs = 0; cs < 6; cs++)
        #pragma unroll
        for (int r = 0; r < 16; r++) {
            int q = (r & 3) + 8 * (r >> 2) + 4 * hi;
            obase[(size_t)q * CDIM + cs * 32 + L31] = (_Float16)acc[cs][r];
        }
}

// ---------------------------------------------------------------------------
// Kernel 3: merge NS splits, normalize (log2 domain), transpose to out[b][c][n]
// ---------------------------------------------------------------------------
template<int NS>
__global__ __launch_bounds__(256) void combine_kernel(
    const _Float16* __restrict__ O_part, const float* __restrict__ m_part,
    const float* __restrict__ l_part, float* __restrict__ out)
{
    __shared__ float Cs[CDIM][33];
    __shared__ float winv[NS][32];
    const int tid = threadIdx.x;
    const int b  = blockIdx.y;
    const int n0 = blockIdx.x * 32;

    if (tid < 32) {
        int n = n0 + tid;
        float mm[NS], ll[NS], ms = -__builtin_inff();
        #pragma unroll
        for (int s = 0; s < NS; s++) {
            mm[s] = m_part[(b * NS + s) * NSEQ + n];
            ll[s] = l_part[(b * NS + s) * NSEQ + n];
            ms = fmaxf(ms, mm[s]);
        }
        float denom = 0.f;
        #pragma unroll
        for (int s = 0; s < NS; s++) {
            float w = __builtin_exp2f(mm[s] - ms);
            mm[s] = w;
            denom += w * ll[s];
        }
        #pragma unroll
        for (int s = 0; s < NS; s++) winv[s][tid] = mm[s] / denom;
    }
    __syncthreads();

    for (int i = tid; i < 32 * 96; i += 256) {
        int nl = i / 96, cp = i % 96;
        float v0 = 0.f, v1 = 0.f;
        #pragma unroll
        for (int s = 0; s < NS; s++) {
            h2_t op = *(const h2_t*)(O_part +
                ((size_t)(b * NS + s) * NSEQ + n0 + nl) * CDIM + cp * 2);
            float w = winv[s][nl];
            v0 += w * (float)op[0];
            v1 += w * (float)op[1];
        }
        Cs[cp * 2][nl] = v0;
        Cs[cp * 2 + 1][nl] = v1;
    }
    __syncthreads();
    for (int i = tid; i < CDIM * 32; i += 256) {
        int nl = i & 31, c = i >> 5;
        out[((size_t)b * CDIM + c) * NSEQ + n0 + nl] = Cs[c][nl];
    }
}

// ---------------------------------------------------------------------------
extern "C" void kernel_launch(void* const* d_in, const int* in_sizes, int n_in,
                              void* d_out, int out_size, void* d_ws, size_t ws_size,
                              hipStream_t stream)
{
    const float* x  = (const float*)d_in[0];
    const float* Wq = (const float*)d_in[1];
    const float* bq = (const float*)d_in[2];
    const float* Wk = (const float*)d_in[3];
    const float* bk = (const float*)d_in[4];
    const float* Wv = (const float*)d_in[5];
    const float* bv = (const float*)d_in[6];
    float* out = (float*)d_out;

    // workspace layout
    char* ws = (char*)d_ws;
    _Float16* QT = (_Float16*)(ws);                    // 7,077,888 B
    _Float16* KT = (_Float16*)(ws + 7077888);
    _Float16* Vg = (_Float16*)(ws + 14155776);
    char* tail = ws + 21233664;
    _Float16* Wh = (_Float16*)tail;                    // 221,184 B, aliases O_part
    _Float16* O_part = (_Float16*)tail;                // NS * 7,077,888 B (f16)

    wconv_kernel<<<108, 256, 0, stream>>>(Wq, Wk, Wv, Wh);
    proj_kernel<<<432, 256, 0, stream>>>(x, Wh, bq, bk, bv, QT, KT, Vg);

    const size_t need8 = 21233664ull + 8 * 7077888ull + 2 * 589824ull;  // 79,036,416
    const size_t need4 = 21233664ull + 4 * 7077888ull + 2 * 294912ull;  // 50,135,040
    if (ws_size >= need8) {
        float* m_part = (float*)(tail + 8 * 7077888ull);
        float* l_part = (float*)(tail + 8 * 7077888ull + 589824ull);
        flash_kernel<8><<<dim3(72, 8, 2), 256, 0, stream>>>(QT, KT, Vg, O_part, m_part, l_part);
        combine_kernel<8><<<dim3(288, 2), 256, 0, stream>>>(O_part, m_part, l_part, out);
    } else if (ws_size >= need4) {
        float* m_part = (float*)(tail + 4 * 7077888ull);
        float* l_part = (float*)(tail + 4 * 7077888ull + 294912ull);
        flash_kernel<4><<<dim3(72, 4, 2), 256, 0, stream>>>(QT, KT, Vg, O_part, m_part, l_part);
        combine_kernel<4><<<dim3(288, 2), 256, 0, stream>>>(O_part, m_part, l_part, out);
    } else {
        float* m_part = (float*)(tail + 2 * 7077888ull);
        float* l_part = (float*)(tail + 2 * 7077888ull + 147456ull);
        flash_kernel<2><<<dim3(72, 2, 2), 256, 0, stream>>>(QT, KT, Vg, O_part, m_part, l_part);
        combine_kernel<2><<<dim3(288, 2), 256, 0, stream>>>(O_part, m_part, l_part, out);
    }
}

// Round 5
// 301.035 us; speedup vs baseline: 1.3877x; 1.3877x over previous
//
#include <hip/hip_runtime.h>

#define NSEQ  9216
#define CDIM  192
#define LOG2E 1.44269504088896f

typedef _Float16 h8_t  __attribute__((ext_vector_type(8)));
typedef _Float16 h4_t  __attribute__((ext_vector_type(4)));
typedef _Float16 h2_t  __attribute__((ext_vector_type(2)));
typedef float    f4_t  __attribute__((ext_vector_type(4)));
typedef float    f16v  __attribute__((ext_vector_type(16)));

static __device__ inline unsigned pack2(float a, float b) {
    union { h2_t h; unsigned u; } x;
    x.h = (h2_t){(_Float16)a, (_Float16)b};
    return x.u;
}

// ---------------------------------------------------------------------------
// Kernel 0: Wq/Wk/Wv fp32 -> f16 Wh[3][192][192].  Wq pre-scaled by log2e.
// ---------------------------------------------------------------------------
__global__ __launch_bounds__(256) void wconv_kernel(
    const float* __restrict__ Wq, const float* __restrict__ Wk,
    const float* __restrict__ Wv, _Float16* __restrict__ Wh)
{
    int i = blockIdx.x * 256 + threadIdx.x;     // f4 index, 3*9216 total
    if (i >= 3 * 9216) return;
    const float* src = (i < 9216) ? Wq : (i < 18432 ? Wk : Wv);
    float s = (i < 9216) ? LOG2E : 1.f;
    int r = i % 9216;
    f4_t w = ((const f4_t*)src)[r];
    h4_t h = {(_Float16)(w[0]*s), (_Float16)(w[1]*s),
              (_Float16)(w[2]*s), (_Float16)(w[3]*s)};
    ((h4_t*)Wh)[i] = h;
}

// ---------------------------------------------------------------------------
// Kernel 1: QKV projection via 32x32x16 MFMA (one wave per (mat, 32-seq)).
// ---------------------------------------------------------------------------
__global__ __launch_bounds__(256) void proj_kernel(
    const float* __restrict__ x, const _Float16* __restrict__ Wh,
    const float* __restrict__ bq, const float* __restrict__ bk,
    const float* __restrict__ bv,
    _Float16* __restrict__ QT, _Float16* __restrict__ KT, _Float16* __restrict__ Vg)
{
    const int tid  = threadIdx.x;
    const int lane = tid & 63, wave = tid >> 6;
    const int L31  = lane & 31, hi = lane >> 5;
    const int idx  = blockIdx.x * 4 + wave;      // 0..1727
    const int mat  = idx / 576;
    const int rem  = idx % 576;
    const int b    = rem / 288;
    const int n0   = (rem % 288) * 32;
    const int n    = n0 + L31;

    h8_t bf[12];
    #pragma unroll
    for (int t = 0; t < 12; t++) {
        h8_t h;
        #pragma unroll
        for (int j = 0; j < 8; j++)
            h[j] = (_Float16)x[(size_t)(b * CDIM + t * 16 + hi * 8 + j) * NSEQ + n];
        bf[t] = h;
    }

    const _Float16* W = Wh + mat * CDIM * CDIM;
    const float* bias = (mat == 0) ? bq : (mat == 1 ? bk : bv);
    const float bscale = (mat == 0) ? LOG2E : 1.f;

    f16v acc[6];
    #pragma unroll
    for (int s = 0; s < 6; s++)
        #pragma unroll
        for (int r = 0; r < 16; r++) acc[s][r] = 0.f;

    #pragma unroll
    for (int t = 0; t < 12; t++) {
        #pragma unroll
        for (int s = 0; s < 6; s++) {
            h8_t a = *(const h8_t*)(W + (s * 32 + L31) * CDIM + t * 16 + hi * 8);
            acc[s] = __builtin_amdgcn_mfma_f32_32x32x16_f16(a, bf[t], acc[s], 0, 0, 0);
        }
    }

    if (mat < 2) {
        _Float16* dst = ((mat == 0) ? QT : KT) + ((size_t)b * NSEQ + n) * CDIM;
        #pragma unroll
        for (int s = 0; s < 6; s++) {
            #pragma unroll
            for (int g = 0; g < 4; g++) {
                f4_t bb = *(const f4_t*)&bias[s * 32 + 8 * g + 4 * hi];
                h4_t h = {(_Float16)(acc[s][4*g+0] + bb[0] * bscale),
                          (_Float16)(acc[s][4*g+1] + bb[1] * bscale),
                          (_Float16)(acc[s][4*g+2] + bb[2] * bscale),
                          (_Float16)(acc[s][4*g+3] + bb[3] * bscale)};
                *(h4_t*)(dst + s * 32 + 8 * g + 4 * hi) = h;
            }
        }
    } else {
        #pragma unroll
        for (int s = 0; s < 6; s++) {
            #pragma unroll
            for (int g = 0; g < 4; g++) {
                f4_t bb = *(const f4_t*)&bias[s * 32 + 8 * g + 4 * hi];
                #pragma unroll
                for (int r = 0; r < 4; r++) {
                    int o = s * 32 + 8 * g + 4 * hi + r;
                    Vg[((size_t)b * CDIM + o) * NSEQ + n] =
                        (_Float16)(acc[s][4*g+r] + bb[r]);
                }
            }
        }
    }
}

// ---------------------------------------------------------------------------
// Kernel 2: flash attention.
//   KTILE=32, SINGLE K+V LDS buffer, TWO barriers per iter (R2/R3's proven
//   sync pattern), next-tile loads prefetched into registers right after the
//   second barrier so they're in flight during the whole compute phase.
//   S^T = K*Q (D[m=key][n=q]); P->B-operand via lane^32 shuffle exchange
//   (no LDS); PV flipped: D[m=c][n=q], V as A-op, per-lane alpha rescale.
// ---------------------------------------------------------------------------
template<int NSPLIT>
__global__ __launch_bounds__(256, 2) void flash_kernel(
    const _Float16* __restrict__ QT, const _Float16* __restrict__ KTg,
    const _Float16* __restrict__ Vg,
    _Float16* __restrict__ O_part, float* __restrict__ m_part, float* __restrict__ l_part)
{
    constexpr int KPS    = NSEQ / NSPLIT;
    constexpr int KITERS = KPS / 32;
    constexpr int KBUF   = 32 * 200;          // halfwords
    // Sh: staging (K 6400 + V 7680 = 14080 hw) and epilogue transpose
    // (4 waves x 6400 hw = 25600 hw) share the same allocation.
    __shared__ __align__(16) _Float16 Sh[25600];   // 51,200 B

    const int tid  = threadIdx.x;
    const int lane = tid & 63, wave = tid >> 6;
    const int L31  = lane & 31, hi = lane >> 5;
    const int qtile = blockIdx.x, split = blockIdx.y, b = blockIdx.z;
    const int q0 = qtile * 128 + wave * 32;

    // resident Q B-fragments: B[k=c][col=q=L31]
    h8_t qf[12];
    const _Float16* qbase = QT + ((size_t)b * NSEQ + q0 + L31) * CDIM + hi * 8;
    #pragma unroll
    for (int t = 0; t < 12; t++) qf[t] = *(const h8_t*)(qbase + t * 16);

    f16v acc[6];
    #pragma unroll
    for (int s = 0; s < 6; s++)
        #pragma unroll
        for (int r = 0; r < 16; r++) acc[s][r] = 0.f;
    float m_run = -__builtin_inff();
    float l_run = 0.f;

    const _Float16* ksrc = KTg + ((size_t)b * NSEQ + split * KPS) * CDIM;
    const _Float16* vsrc = Vg + (size_t)b * CDIM * NSEQ + split * KPS;

    // staging maps (loop-invariant): 768 h8-chunks each for K and V
    int kds[3], vds[3];
    const _Float16 *kgl[3], *vgl[3];
    #pragma unroll
    for (int r = 0; r < 3; r++) {
        int i = r * 256 + tid;
        kds[r] = (i / 24) * 200 + (i % 24) * 8;
        kgl[r] = ksrc + i * 8;
        int c = i >> 2, seg = i & 3;
        vds[r] = KBUF + c * 40 + seg * 8;
        vgl[r] = vsrc + (size_t)c * NSEQ + seg * 8;
    }

    h8_t kreg[3], vreg[3];
    #pragma unroll
    for (int r = 0; r < 3; r++) kreg[r] = *(const h8_t*)(kgl[r]);
    #pragma unroll
    for (int r = 0; r < 3; r++) vreg[r] = *(const h8_t*)(vgl[r]);

    for (int kt = 0; kt < KITERS; kt++) {
        __syncthreads();                    // prev iter's LDS reads done
        #pragma unroll
        for (int r = 0; r < 3; r++) *(h8_t*)(Sh + kds[r]) = kreg[r];
        #pragma unroll
        for (int r = 0; r < 3; r++) *(h8_t*)(Sh + vds[r]) = vreg[r];
        __syncthreads();                    // LDS tile ready
        if (kt + 1 < KITERS) {              // loads in flight through this iter
            #pragma unroll
            for (int r = 0; r < 3; r++)
                kreg[r] = *(const h8_t*)(kgl[r] + (kt + 1) * 32 * CDIM);
            #pragma unroll
            for (int r = 0; r < 3; r++)
                vreg[r] = *(const h8_t*)(vgl[r] + (kt + 1) * 32);
        }

        // S^T[key][q]: A = K[key=L31][c], B = qf
        f16v st;
        #pragma unroll
        for (int r = 0; r < 16; r++) st[r] = 0.f;
        #pragma unroll
        for (int t = 0; t < 12; t++) {
            h8_t a = *(const h8_t*)(Sh + L31 * 200 + t * 16 + hi * 8);
            st = __builtin_amdgcn_mfma_f32_32x32x16_f16(a, qf[t], st, 0, 0, 0);
        }

        // online softmax (log2 domain), q = L31; this half holds 16 keys
        float mx = st[0];
        #pragma unroll
        for (int r = 1; r < 16; r++) mx = fmaxf(mx, st[r]);
        mx = fmaxf(mx, __shfl_xor(mx, 32));
        float m_new = fmaxf(m_run, mx);

        float p[16], psum = 0.f;
        #pragma unroll
        for (int r = 0; r < 16; r++) {
            p[r] = __builtin_exp2f(st[r] - m_new);
            psum += p[r];
        }

        if (__any(m_new > m_run)) {
            float alpha = __builtin_exp2f(m_run - m_new);   // per-lane (q=L31)
            l_run = l_run * alpha + psum;
            #pragma unroll
            for (int cs = 0; cs < 6; cs++)
                #pragma unroll
                for (int r = 0; r < 16; r++) acc[cs][r] *= alpha;
        } else {
            l_run += psum;
        }
        m_run = m_new;

        // pack P: pk[2t+e] holds keys 8t+4hi+{2e,2e+1} (key of p[r] = (r&3)+8(r>>2)+4hi)
        unsigned pk[8];
        #pragma unroll
        for (int t2 = 0; t2 < 4; t2++) {
            pk[2*t2]   = pack2(p[4*t2+0], p[4*t2+1]);
            pk[2*t2+1] = pack2(p[4*t2+2], p[4*t2+3]);
        }
        // exchange with lane^32: each side sends what its partner needs
        unsigned recv0 = __shfl_xor(hi ? pk[0] : pk[2], 32);
        unsigned recv1 = __shfl_xor(hi ? pk[1] : pk[3], 32);
        unsigned recv2 = __shfl_xor(hi ? pk[4] : pk[6], 32);
        unsigned recv3 = __shfl_xor(hi ? pk[5] : pk[7], 32);

        union { h8_t h; unsigned u[4]; } pb0, pb1;
        pb0.u[0] = hi ? recv0 : pk[0];
        pb0.u[1] = hi ? recv1 : pk[1];
        pb0.u[2] = hi ? pk[2] : recv0;
        pb0.u[3] = hi ? pk[3] : recv1;
        pb1.u[0] = hi ? recv2 : pk[4];
        pb1.u[1] = hi ? recv3 : pk[5];
        pb1.u[2] = hi ? pk[6] : recv2;
        pb1.u[3] = hi ? pk[7] : recv3;

        // PV flipped: D[m=c][n=q] += V[c][key] * P^T[key][q]
        #pragma unroll
        for (int ks = 0; ks < 2; ks++) {
            h8_t pb = ks ? pb1.h : pb0.h;
            #pragma unroll
            for (int cs = 0; cs < 6; cs++) {
                h8_t va = *(const h8_t*)(Sh + KBUF + (cs * 32 + L31) * 40 + ks * 16 + hi * 8);
                acc[cs] = __builtin_amdgcn_mfma_f32_32x32x16_f16(va, pb, acc[cs], 0, 0, 0);
            }
        }
    }

    // epilogue
    float l_tot = l_run + __shfl_xor(l_run, 32);
    const size_t pw = (size_t)(b * NSPLIT + split) * NSEQ + q0;
    if (lane < 32) {
        m_part[pw + lane] = m_run;
        l_part[pw + lane] = l_tot;
    }
    __syncthreads();                       // all LDS reads of Sh done
    // per-wave transpose through LDS: acc rows are c, cols are q
    _Float16* T = Sh + wave * 6400;
    #pragma unroll
    for (int cs = 0; cs < 6; cs++)
        #pragma unroll
        for (int g = 0; g < 4; g++) {
            h4_t hh = {(_Float16)acc[cs][4*g+0], (_Float16)acc[cs][4*g+1],
                       (_Float16)acc[cs][4*g+2], (_Float16)acc[cs][4*g+3]};
            // c = cs*32 + 8g + 4hi + j, row q = L31
            *(h4_t*)(T + L31 * 200 + cs * 32 + 8 * g + 4 * hi) = hh;
        }
    _Float16* ob = O_part + pw * CDIM;
    #pragma unroll
    for (int it = 0; it < 12; it++) {
        int i = it * 64 + lane;
        int qq = i / 24, col = i % 24;
        h8_t h = *(const h8_t*)(T + qq * 200 + col * 8);
        *(h8_t*)(ob + (size_t)qq * CDIM + col * 8) = h;
    }
}

// ---------------------------------------------------------------------------
// Kernel 3: merge NS splits, normalize (log2 domain), transpose to out[b][c][n]
// ---------------------------------------------------------------------------
template<int NS>
__global__ __launch_bounds__(256) void combine_kernel(
    const _Float16* __restrict__ O_part, const float* __restrict__ m_part,
    const float* __restrict__ l_part, float* __restrict__ out)
{
    __shared__ float Cs[CDIM][33];
    __shared__ float winv[NS][32];
    const int tid = threadIdx.x;
    const int b  = blockIdx.y;
    const int n0 = blockIdx.x * 32;

    if (tid < 32) {
        int n = n0 + tid;
        float mm[NS], ll[NS], ms = -__builtin_inff();
        #pragma unroll
        for (int s = 0; s < NS; s++) {
            mm[s] = m_part[(b * NS + s) * NSEQ + n];
            ll[s] = l_part[(b * NS + s) * NSEQ + n];
            ms = fmaxf(ms, mm[s]);
        }
        float denom = 0.f;
        #pragma unroll
        for (int s = 0; s < NS; s++) {
            float w = __builtin_exp2f(mm[s] - ms);
            mm[s] = w;
            denom += w * ll[s];
        }
        #pragma unroll
        for (int s = 0; s < NS; s++) winv[s][tid] = mm[s] / denom;
    }
    __syncthreads();

    for (int i = tid; i < 32 * 96; i += 256) {
        int nl = i / 96, cp = i % 96;
        float v0 = 0.f, v1 = 0.f;
        #pragma unroll
        for (int s = 0; s < NS; s++) {
            h2_t op = *(const h2_t*)(O_part +
                ((size_t)(b * NS + s) * NSEQ + n0 + nl) * CDIM + cp * 2);
            float w = winv[s][nl];
            v0 += w * (float)op[0];
            v1 += w * (float)op[1];
        }
        Cs[cp * 2][nl] = v0;
        Cs[cp * 2 + 1][nl] = v1;
    }
    __syncthreads();
    for (int i = tid; i < CDIM * 32; i += 256) {
        int nl = i & 31, c = i >> 5;
        out[((size_t)b * CDIM + c) * NSEQ + n0 + nl] = Cs[c][nl];
    }
}

// ---------------------------------------------------------------------------
extern "C" void kernel_launch(void* const* d_in, const int* in_sizes, int n_in,
                              void* d_out, int out_size, void* d_ws, size_t ws_size,
                              hipStream_t stream)
{
    const float* x  = (const float*)d_in[0];
    const float* Wq = (const float*)d_in[1];
    const float* bq = (const float*)d_in[2];
    const float* Wk = (const float*)d_in[3];
    const float* bk = (const float*)d_in[4];
    const float* Wv = (const float*)d_in[5];
    const float* bv = (const float*)d_in[6];
    float* out = (float*)d_out;

    // workspace layout
    char* ws = (char*)d_ws;
    _Float16* QT = (_Float16*)(ws);                    // 7,077,888 B
    _Float16* KT = (_Float16*)(ws + 7077888);
    _Float16* Vg = (_Float16*)(ws + 14155776);
    char* tail = ws + 21233664;
    _Float16* Wh = (_Float16*)tail;                    // 221,184 B, aliases O_part
    _Float16* O_part = (_Float16*)tail;                // NS * 7,077,888 B (f16)

    wconv_kernel<<<108, 256, 0, stream>>>(Wq, Wk, Wv, Wh);
    proj_kernel<<<432, 256, 0, stream>>>(x, Wh, bq, bk, bv, QT, KT, Vg);

    const size_t need8 = 21233664ull + 8 * 7077888ull + 2 * 589824ull;  // 79,036,416
    const size_t need4 = 21233664ull + 4 * 7077888ull + 2 * 294912ull;  // 50,135,040
    if (ws_size >= need8) {
        float* m_part = (float*)(tail + 8 * 7077888ull);
        float* l_part = (float*)(tail + 8 * 7077888ull + 589824ull);
        flash_kernel<8><<<dim3(72, 8, 2), 256, 0, stream>>>(QT, KT, Vg, O_part, m_part, l_part);
        combine_kernel<8><<<dim3(288, 2), 256, 0, stream>>>(O_part, m_part, l_part, out);
    } else if (ws_size >= need4) {
        float* m_part = (float*)(tail + 4 * 7077888ull);
        float* l_part = (float*)(tail + 4 * 7077888ull + 294912ull);
        flash_kernel<4><<<dim3(72, 4, 2), 256, 0, stream>>>(QT, KT, Vg, O_part, m_part, l_part);
        combine_kernel<4><<<dim3(288, 2), 256, 0, stream>>>(O_part, m_part, l_part, out);
    } else {
        float* m_part = (float*)(tail + 2 * 7077888ull);
        float* l_part = (float*)(tail + 2 * 7077888ull + 147456ull);
        flash_kernel<2><<<dim3(72, 2, 2), 256, 0, stream>>>(QT, KT, Vg, O_part, m_part, l_part);
        combine_kernel<2><<<dim3(288, 2), 256, 0, stream>>>(O_part, m_part, l_part, out);
    }
}